// Round 4
// baseline (482.058 us; speedup 1.0000x reference)
//
#include <hip/hip_runtime.h>

// ---------------------------------------------------------------------------
// Self-attention (single head, causal), B=2, T=4096, C=1024, fp32 in/out.
// Strategy: cast to bf16, run everything as m97-structure 128x128 MFMA GEMMs.
//   q = x@Wq^T ; k = x@Wk^T ; vT = (x@Wv^T)^T
//   S = q@k^T * 1/32  (fp32, lower-triangle blocks only)
//   P = softmax_causal(S) in-place (fp32)
//   attOut = P@v = gemm_bt(P_f32, vT_bf16)  (A staged fp32->bf16 in regs)
//   out = attOut@Wo^T + bo (fp32)
// ---------------------------------------------------------------------------

typedef __attribute__((ext_vector_type(8))) short bf16x8;
typedef __attribute__((ext_vector_type(4))) float f32x4;

#define AS1 __attribute__((address_space(1)))
#define AS3 __attribute__((address_space(3)))

static constexpr int Bz = 2;
static constexpr int T = 4096;
static constexpr int C = 1024;

__device__ __forceinline__ unsigned short f2bf(float f) {
  unsigned int u = __float_as_uint(f);
  u += 0x7FFFu + ((u >> 16) & 1u);
  return (unsigned short)(u >> 16);
}

// ---------------------------------------------------------------------------
// Cast x (8388608) + Wq/Wk/Wv/Wo (1048576 each) fp32 -> bf16, vectorized x4.
// ---------------------------------------------------------------------------
__global__ __launch_bounds__(256) void cast_all_bf16(
    const float* __restrict__ x, const float* __restrict__ wq,
    const float* __restrict__ wk, const float* __restrict__ wv,
    const float* __restrict__ wo, unsigned short* __restrict__ xb,
    unsigned short* __restrict__ wqb, unsigned short* __restrict__ wkb,
    unsigned short* __restrict__ wvb, unsigned short* __restrict__ wob) {
  const size_t NX = (size_t)Bz * T * C;       // 8388608
  const size_t NW = (size_t)C * C;            // 1048576
  size_t i4 = ((size_t)blockIdx.x * 256 + threadIdx.x) * 4;
  const float* src;
  unsigned short* dst;
  size_t off;
  if (i4 < NX) {
    src = x; dst = xb; off = i4;
  } else {
    size_t j = i4 - NX;
    int w = (int)(j >> 20);
    off = j & (NW - 1);
    if (w == 0)      { src = wq; dst = wqb; }
    else if (w == 1) { src = wk; dst = wkb; }
    else if (w == 2) { src = wv; dst = wvb; }
    else             { src = wo; dst = wob; }
  }
  float4 f = *(const float4*)(src + off);
  ushort4 u;
  u.x = f2bf(f.x); u.y = f2bf(f.y); u.z = f2bf(f.z); u.w = f2bf(f.w);
  *(ushort4*)(dst + off) = u;
}

// ---------------------------------------------------------------------------
// gemm_bt: C[m][n] = scale * sum_k A[m][k] * B[n][k]   (B given row-major N x K)
//   OUT_MODE 0: fp32 out (optional bias), row stride N
//   OUT_MODE 1: bf16 out, row stride N
//   OUT_MODE 2: bf16 out transposed: out[b][n][t], b = m/Ttr, t = m%Ttr
//   A_F32: A is fp32, staged to LDS with reg convert (else bf16 global_load_lds)
//   CAUSAL 0: none; 1: skip blocks with bx>by (S gemm); 2: ktiles=(by+1)*4 (PV)
// Tile 128x128, BK=32, 256 threads = 4 waves (2x2), mfma_f32_16x16x32_bf16.
// ---------------------------------------------------------------------------
template <int OUT_MODE, bool A_F32, bool BIAS, int CAUSAL>
__global__ __launch_bounds__(256) void gemm_bt(
    const void* __restrict__ Ap, const unsigned short* __restrict__ Bp,
    void* __restrict__ Cp, const float* __restrict__ bias,
    int M, int N, int K, int lda, int ldb,
    long long batchA, long long batchB, long long batchC,
    float scale, int Ttr) {
  const int bx = blockIdx.x, by = blockIdx.y, bz = blockIdx.z;
  if (CAUSAL == 1 && bx > by) return;
  const int m0 = by * 128, n0 = bx * 128;
  int ktiles = K / 32;
  if (CAUSAL == 2) ktiles = (by + 1) * 4;

  const unsigned short* A16 = (const unsigned short*)Ap + (size_t)bz * (A_F32 ? 0 : batchA);
  const float* A32 = (const float*)Ap + (size_t)bz * (A_F32 ? batchA : 0);
  const unsigned short* Bb = Bp + (size_t)bz * batchB;

  __shared__ __align__(16) unsigned short As[128 * 32];
  __shared__ __align__(16) unsigned short Bs[128 * 32];

  const int tid = threadIdx.x;
  const int lane = tid & 63;
  const int wid = tid >> 6;
  const int wr = wid >> 1, wc = wid & 1;
  const int lhi = lane >> 4, llo = lane & 15;

  f32x4 acc[4][4] = {};

  for (int kt = 0; kt < ktiles; ++kt) {
    __syncthreads();
    // ---- stage A tile [128][32] ----
    if (A_F32) {
      const int row = tid >> 1, half = tid & 1;
      const float* src = A32 + (size_t)(m0 + row) * lda + kt * 32 + half * 16;
      float4 fa = *(const float4*)(src + 0);
      float4 fb = *(const float4*)(src + 4);
      float4 fc = *(const float4*)(src + 8);
      float4 fd = *(const float4*)(src + 12);
      bf16x8 lo, hi;
      lo[0] = f2bf(fa.x); lo[1] = f2bf(fa.y); lo[2] = f2bf(fa.z); lo[3] = f2bf(fa.w);
      lo[4] = f2bf(fb.x); lo[5] = f2bf(fb.y); lo[6] = f2bf(fb.z); lo[7] = f2bf(fb.w);
      hi[0] = f2bf(fc.x); hi[1] = f2bf(fc.y); hi[2] = f2bf(fc.z); hi[3] = f2bf(fc.w);
      hi[4] = f2bf(fd.x); hi[5] = f2bf(fd.y); hi[6] = f2bf(fd.z); hi[7] = f2bf(fd.w);
      *(bf16x8*)&As[row * 32 + half * 16 + 0] = lo;
      *(bf16x8*)&As[row * 32 + half * 16 + 8] = hi;
    } else {
#pragma unroll
      for (int i = 0; i < 2; ++i) {
        int loff = wid * 2048 + i * 1024 + lane * 16;  // byte offset in 8KB A tile
        int row = loff >> 6, colb = loff & 63;
        const char* src =
            (const char*)(A16 + (size_t)(m0 + row) * lda + kt * 32) + colb;
        __builtin_amdgcn_global_load_lds(
            (const AS1 char*)src,
            (AS3 char*)((char*)As + wid * 2048 + i * 1024), 16, 0, 0);
      }
    }
    // ---- stage B tile [128][32] ----
#pragma unroll
    for (int i = 0; i < 2; ++i) {
      int loff = wid * 2048 + i * 1024 + lane * 16;
      int row = loff >> 6, colb = loff & 63;
      const char* src =
          (const char*)(Bb + (size_t)(n0 + row) * ldb + kt * 32) + colb;
      __builtin_amdgcn_global_load_lds(
          (const AS1 char*)src,
          (AS3 char*)((char*)Bs + wid * 2048 + i * 1024), 16, 0, 0);
    }
    __syncthreads();
    // ---- compute: 16 MFMA ----
    bf16x8 af[4], bfr[4];
#pragma unroll
    for (int mi = 0; mi < 4; ++mi)
      af[mi] = *(const bf16x8*)&As[(wr * 64 + mi * 16 + llo) * 32 + lhi * 8];
#pragma unroll
    for (int ni = 0; ni < 4; ++ni)
      bfr[ni] = *(const bf16x8*)&Bs[(wc * 64 + ni * 16 + llo) * 32 + lhi * 8];
#pragma unroll
    for (int mi = 0; mi < 4; ++mi)
#pragma unroll
      for (int ni = 0; ni < 4; ++ni)
        acc[mi][ni] = __builtin_amdgcn_mfma_f32_16x16x32_bf16(
            af[mi], bfr[ni], acc[mi][ni], 0, 0, 0);
  }

  // ---- epilogue ----
  int b_tr = 0, tbase = 0;
  if (OUT_MODE == 2) { b_tr = m0 / Ttr; tbase = m0 - b_tr * Ttr; }
#pragma unroll
  for (int mi = 0; mi < 4; ++mi) {
#pragma unroll
    for (int ni = 0; ni < 4; ++ni) {
      f32x4 v = acc[mi][ni];
      const int r0 = wr * 64 + mi * 16 + lhi * 4;
      const int c = wc * 64 + ni * 16 + llo;
      const int gn = n0 + c;
#pragma unroll
      for (int j = 0; j < 4; ++j) {
        const int r = r0 + j;
        const int gm = m0 + r;
        float val = v[j] * scale;
        if (BIAS) val += bias[gn];
        if (OUT_MODE == 0) {
          float* Co = (float*)Cp + (size_t)bz * batchC;
          Co[(size_t)gm * N + gn] = val;
        } else if (OUT_MODE == 1) {
          unsigned short* Co = (unsigned short*)Cp + (size_t)bz * batchC;
          Co[(size_t)gm * N + gn] = f2bf(val);
        } else {
          unsigned short* Co = (unsigned short*)Cp;
          const int t = tbase + r;
          Co[(size_t)b_tr * ((size_t)N * Ttr) + (size_t)gn * Ttr + t] = f2bf(val);
        }
      }
    }
  }
}

// ---------------------------------------------------------------------------
// Causal row softmax, in place on fp32 S[b][t][0..T). Row t: valid s in [0,t];
// writes normalized p for s<=t and zeros up to the next 128 boundary (what the
// PV gemm's K loop will read). One block per row.
// ---------------------------------------------------------------------------
__global__ __launch_bounds__(256) void softmax_causal(float* __restrict__ S) {
  const int r = blockIdx.x;           // 0 .. Bz*T-1
  const int b = r >> 12;              // T = 4096
  const int t = r & (T - 1);
  float* row = S + (size_t)b * T * T + (size_t)t * T;
  const int n = t + 1;
  const int nw = ((t >> 7) + 1) << 7;  // write extent, multiple of 128

  __shared__ float buf[T];
  __shared__ float red[4];
  const int tid = threadIdx.x;

  float lmax = -1e30f;
  for (int i = tid * 4; i < nw; i += 1024) {
    float4 f = *(const float4*)(row + i);
    ((float4*)buf)[i >> 2] = f;
    if (i + 0 < n) lmax = fmaxf(lmax, f.x);
    if (i + 1 < n) lmax = fmaxf(lmax, f.y);
    if (i + 2 < n) lmax = fmaxf(lmax, f.z);
    if (i + 3 < n) lmax = fmaxf(lmax, f.w);
  }
#pragma unroll
  for (int o = 32; o > 0; o >>= 1) lmax = fmaxf(lmax, __shfl_xor(lmax, o));
  if ((tid & 63) == 0) red[tid >> 6] = lmax;
  __syncthreads();
  const float m = fmaxf(fmaxf(red[0], red[1]), fmaxf(red[2], red[3]));
  __syncthreads();

  float lsum = 0.f;
  for (int i = tid; i < nw; i += 256) {
    float p = (i < n) ? __expf(buf[i] - m) : 0.f;
    buf[i] = p;
    lsum += p;
  }
#pragma unroll
  for (int o = 32; o > 0; o >>= 1) lsum += __shfl_xor(lsum, o);
  if ((tid & 63) == 0) red[tid >> 6] = lsum;
  __syncthreads();
  const float inv = 1.f / (red[0] + red[1] + red[2] + red[3]);

  for (int i = tid * 4; i < nw; i += 1024) {
    float4 p = ((const float4*)buf)[i >> 2];
    p.x *= inv; p.y *= inv; p.z *= inv;
    p.w *= inv;
    *(float4*)(row + i) = p;
  }
}

// ---------------------------------------------------------------------------
extern "C" void kernel_launch(void* const* d_in, const int* in_sizes, int n_in,
                              void* d_out, int out_size, void* d_ws,
                              size_t ws_size, hipStream_t stream) {
  const float* x  = (const float*)d_in[0];
  const float* Wq = (const float*)d_in[1];
  const float* Wk = (const float*)d_in[2];
  const float* Wv = (const float*)d_in[3];
  const float* Wo = (const float*)d_in[4];
  const float* bo = (const float*)d_in[5];
  float* out = (float*)d_out;
  char* ws = (char*)d_ws;

  const size_t MB = 1024 * 1024;
  unsigned short* Wqb = (unsigned short*)(ws + 0 * MB);
  unsigned short* Wkb = (unsigned short*)(ws + 2 * MB);
  unsigned short* Wvb = (unsigned short*)(ws + 4 * MB);
  unsigned short* Wob = (unsigned short*)(ws + 6 * MB);
  unsigned short* xb  = (unsigned short*)(ws + 8 * MB);   // 16 MB
  unsigned short* qb  = (unsigned short*)(ws + 24 * MB);  // 16 MB
  unsigned short* kb  = (unsigned short*)(ws + 40 * MB);  // 16 MB
  unsigned short* vTb = (unsigned short*)(ws + 56 * MB);  // 16 MB
  float* S            = (float*)(ws + 72 * MB);           // 128 MB
  unsigned short* attO = (unsigned short*)(ws + 8 * MB);  // alias xb (dead then)
  (void)ws_size; (void)in_sizes; (void)n_in; (void)out_size;

  const dim3 blk(256);
  const long long TC = (long long)T * C;
  const long long TT = (long long)T * T;

  // 0) casts
  cast_all_bf16<<<12288, blk, 0, stream>>>(x, Wq, Wk, Wv, Wo,
                                           xb, Wqb, Wkb, Wvb, Wob);
  // 1) projections: M=8192, N=1024, K=1024
  gemm_bt<1, false, false, 0><<<dim3(8, 64, 1), blk, 0, stream>>>(
      xb, Wqb, qb, nullptr, Bz * T, C, C, C, C, 0, 0, 0, 1.f, 0);
  gemm_bt<1, false, false, 0><<<dim3(8, 64, 1), blk, 0, stream>>>(
      xb, Wkb, kb, nullptr, Bz * T, C, C, C, C, 0, 0, 0, 1.f, 0);
  gemm_bt<2, false, false, 0><<<dim3(8, 64, 1), blk, 0, stream>>>(
      xb, Wvb, vTb, nullptr, Bz * T, C, C, C, C, 0, 0, 0, 1.f, T);
  // 2) S = q k^T * 1/sqrt(C)   (causal: lower-triangle blocks only)
  gemm_bt<0, false, false, 1><<<dim3(32, 32, 2), blk, 0, stream>>>(
      qb, kb, S, nullptr, T, T, C, C, C, TC, TC, TT, 0.03125f, 0);
  // 3) causal softmax in place
  softmax_causal<<<Bz * T, blk, 0, stream>>>(S);
  // 4) attOut = P @ v  (A fp32 staged, B = vT, K-loop truncated at diagonal)
  gemm_bt<1, true, false, 2><<<dim3(8, 32, 2), blk, 0, stream>>>(
      S, vTb, attO, nullptr, T, C, T, T, T, TT, TC, TC, 1.f, 0);
  // 5) out = attOut @ Wo^T + bo
  gemm_bt<0, false, true, 0><<<dim3(8, 64, 1), blk, 0, stream>>>(
      attO, Wob, out, bo, Bz * T, C, C, C, C, 0, 0, 0, 1.f, 0);
}

// Round 9
// 436.687 us; speedup vs baseline: 1.1039x; 1.1039x over previous
//
#include <hip/hip_runtime.h>

// ---------------------------------------------------------------------------
// Self-attention (single head, causal), B=2, T=4096, C=1024, fp32 in/out.
//   cast:   x, Wq|Wk|Wv (contiguous), Wo -> bf16
//   QKV:    one GEMM M=8192,N=3072,K=1024; epilogue routes q/k row-major,
//           v transposed (vT[b][d][t])
//   S:      q k^T * 1/32, fp32, lower-triangle blocks only
//   softmax: causal, in place; OUTPUT bf16 (P) overlaid on S rows (stride 2T)
//   PV:     attO = P @ v, bf16 fast path, K truncated at diagonal, heavy-first
//   O:      out = attO @ Wo^T + bo (fp32)
// ---------------------------------------------------------------------------

typedef __attribute__((ext_vector_type(8))) short bf16x8;
typedef __attribute__((ext_vector_type(4))) float f32x4;

#define AS1 __attribute__((address_space(1)))
#define AS3 __attribute__((address_space(3)))

static constexpr int Bz = 2;
static constexpr int T = 4096;
static constexpr int C = 1024;

__device__ __forceinline__ unsigned short f2bf(float f) {
  unsigned int u = __float_as_uint(f);
  u += 0x7FFFu + ((u >> 16) & 1u);
  return (unsigned short)(u >> 16);
}

// ---------------------------------------------------------------------------
// Cast x + Wq/Wk/Wv/Wo fp32 -> bf16 (dsts laid out so Wq|Wk|Wv contiguous).
// ---------------------------------------------------------------------------
__global__ __launch_bounds__(256) void cast_all_bf16(
    const float* __restrict__ x, const float* __restrict__ wq,
    const float* __restrict__ wk, const float* __restrict__ wv,
    const float* __restrict__ wo, unsigned short* __restrict__ xb,
    unsigned short* __restrict__ wqb, unsigned short* __restrict__ wkb,
    unsigned short* __restrict__ wvb, unsigned short* __restrict__ wob) {
  const size_t NX = (size_t)Bz * T * C;       // 8388608
  const size_t NW = (size_t)C * C;            // 1048576
  size_t i4 = ((size_t)blockIdx.x * 256 + threadIdx.x) * 4;
  const float* src;
  unsigned short* dst;
  size_t off;
  if (i4 < NX) {
    src = x; dst = xb; off = i4;
  } else {
    size_t j = i4 - NX;
    int w = (int)(j >> 20);
    off = j & (NW - 1);
    if (w == 0)      { src = wq; dst = wqb; }
    else if (w == 1) { src = wk; dst = wkb; }
    else if (w == 2) { src = wv; dst = wvb; }
    else             { src = wo; dst = wob; }
  }
  float4 f = *(const float4*)(src + off);
  ushort4 u;
  u.x = f2bf(f.x); u.y = f2bf(f.y); u.z = f2bf(f.z); u.w = f2bf(f.w);
  *(ushort4*)(dst + off) = u;
}

// ---------------------------------------------------------------------------
// gemm_bt: C[m][n] = scale * sum_k A[m][k] * B[n][k]; A,B bf16 row-major.
//   OUT_MODE 0: fp32 out (optional bias), row stride N
//   OUT_MODE 1: bf16 out, row stride N
//   OUT_MODE 3: QKV split: gn<1024 -> Cp (q), <2048 -> Cp2 (k), else Cp3 = vT
//               transposed [b][d][t] with b = gm>>12, t = gm&4095
//   CAUSAL 0: none; 1: skip blocks bx>by (S); 2: ktiles=(by+1)*4, by reversed
//             heavy-first (PV)
// Tile 128x128, BK=32, 256 threads = 4 waves (2x2), mfma_f32_16x16x32_bf16,
// global_load_lds width-16 staging on both operands.
// ---------------------------------------------------------------------------
template <int OUT_MODE, bool BIAS, int CAUSAL>
__global__ __launch_bounds__(256) void gemm_bt(
    const unsigned short* __restrict__ Ap, const unsigned short* __restrict__ Bp,
    void* __restrict__ Cp, void* __restrict__ Cp2, void* __restrict__ Cp3,
    const float* __restrict__ bias, int N, int K, int lda, int ldb,
    long long batchA, long long batchB, long long batchC, float scale) {
  const int bx = blockIdx.x, bz = blockIdx.z;
  const int by = (CAUSAL == 2) ? ((int)gridDim.y - 1 - (int)blockIdx.y)
                               : (int)blockIdx.y;
  if (CAUSAL == 1 && bx > by) return;
  const int m0 = by * 128, n0 = bx * 128;
  int ktiles = K / 32;
  if (CAUSAL == 2) ktiles = (by + 1) * 4;

  const unsigned short* Ab = Ap + (size_t)bz * batchA;
  const unsigned short* Bb = Bp + (size_t)bz * batchB;

  __shared__ __align__(16) unsigned short As[128 * 32];
  __shared__ __align__(16) unsigned short Bs[128 * 32];

  const int tid = threadIdx.x;
  const int lane = tid & 63;
  const int wid = tid >> 6;
  const int wr = wid >> 1, wc = wid & 1;
  const int lhi = lane >> 4, llo = lane & 15;

  f32x4 acc[4][4] = {};

  for (int kt = 0; kt < ktiles; ++kt) {
    __syncthreads();
    // ---- stage A and B tiles [128 rows][32 bf16] via global_load_lds x16 ----
#pragma unroll
    for (int i = 0; i < 2; ++i) {
      int loff = wid * 2048 + i * 1024 + lane * 16;  // byte offset in 8KB tile
      int row = loff >> 6, colb = loff & 63;
      const char* srcA =
          (const char*)(Ab + (size_t)(m0 + row) * lda + kt * 32) + colb;
      __builtin_amdgcn_global_load_lds(
          (const AS1 char*)srcA,
          (AS3 char*)((char*)As + wid * 2048 + i * 1024), 16, 0, 0);
      const char* srcB =
          (const char*)(Bb + (size_t)(n0 + row) * ldb + kt * 32) + colb;
      __builtin_amdgcn_global_load_lds(
          (const AS1 char*)srcB,
          (AS3 char*)((char*)Bs + wid * 2048 + i * 1024), 16, 0, 0);
    }
    __syncthreads();
    // ---- compute: 16 MFMA ----
    bf16x8 af[4], bfr[4];
#pragma unroll
    for (int mi = 0; mi < 4; ++mi)
      af[mi] = *(const bf16x8*)&As[(wr * 64 + mi * 16 + llo) * 32 + lhi * 8];
#pragma unroll
    for (int ni = 0; ni < 4; ++ni)
      bfr[ni] = *(const bf16x8*)&Bs[(wc * 64 + ni * 16 + llo) * 32 + lhi * 8];
#pragma unroll
    for (int mi = 0; mi < 4; ++mi)
#pragma unroll
      for (int ni = 0; ni < 4; ++ni)
        acc[mi][ni] = __builtin_amdgcn_mfma_f32_16x16x32_bf16(
            af[mi], bfr[ni], acc[mi][ni], 0, 0, 0);
  }

  // ---- epilogue ----
#pragma unroll
  for (int mi = 0; mi < 4; ++mi) {
#pragma unroll
    for (int ni = 0; ni < 4; ++ni) {
      f32x4 v = acc[mi][ni];
      const int r0 = wr * 64 + mi * 16 + lhi * 4;
      const int c = wc * 64 + ni * 16 + llo;
      const int gn = n0 + c;
#pragma unroll
      for (int j = 0; j < 4; ++j) {
        const int r = r0 + j;
        const int gm = m0 + r;
        float val = v[j] * scale;
        if (BIAS) val += bias[gn];
        if (OUT_MODE == 0) {
          float* Co = (float*)Cp + (size_t)bz * batchC;
          Co[(size_t)gm * N + gn] = val;
        } else if (OUT_MODE == 1) {
          unsigned short* Co = (unsigned short*)Cp + (size_t)bz * batchC;
          Co[(size_t)gm * N + gn] = f2bf(val);
        } else {  // OUT_MODE 3: QKV split
          if (gn < 1024) {
            ((unsigned short*)Cp)[(size_t)gm * 1024 + gn] = f2bf(val);
          } else if (gn < 2048) {
            ((unsigned short*)Cp2)[(size_t)gm * 1024 + (gn - 1024)] = f2bf(val);
          } else {
            const int b = gm >> 12, t = gm & (T - 1);
            ((unsigned short*)Cp3)[(size_t)b * T * C +
                                   (size_t)(gn - 2048) * T + t] = f2bf(val);
          }
        }
      }
    }
  }
}

// ---------------------------------------------------------------------------
// Causal row softmax. Reads fp32 S row [0, nw); writes bf16 P IN PLACE over
// the row start (stride stays T floats = 2T bf16). Row t: p for s<=t,
// zeros up to nw = next 128 boundary (exact extent the PV gemm reads).
// Safe in place: full row is in LDS before any global write.
// ---------------------------------------------------------------------------
__global__ __launch_bounds__(256) void softmax_causal(float* __restrict__ S) {
  const int r = blockIdx.x;           // 0 .. Bz*T-1
  const int b = r >> 12;              // T = 4096
  const int t = r & (T - 1);
  float* row = S + (size_t)b * T * T + (size_t)t * T;
  const int n = t + 1;
  const int nw = ((t >> 7) + 1) << 7;  // extent, multiple of 128

  __shared__ float buf[T];
  __shared__ float red[4];
  const int tid = threadIdx.x;

  float lmax = -1e30f;
  for (int i = tid * 4; i < nw; i += 1024) {
    float4 f = *(const float4*)(row + i);
    ((float4*)buf)[i >> 2] = f;
    if (i + 0 < n) lmax = fmaxf(lmax, f.x);
    if (i + 1 < n) lmax = fmaxf(lmax, f.y);
    if (i + 2 < n) lmax = fmaxf(lmax, f.z);
    if (i + 3 < n) lmax = fmaxf(lmax, f.w);
  }
#pragma unroll
  for (int o = 32; o > 0; o >>= 1) lmax = fmaxf(lmax, __shfl_xor(lmax, o));
  if ((tid & 63) == 0) red[tid >> 6] = lmax;
  __syncthreads();
  const float m = fmaxf(fmaxf(red[0], red[1]), fmaxf(red[2], red[3]));
  __syncthreads();

  float lsum = 0.f;
  for (int i = tid; i < nw; i += 256) {
    float p = (i < n) ? __expf(buf[i] - m) : 0.f;
    buf[i] = p;
    lsum += p;
  }
#pragma unroll
  for (int o = 32; o > 0; o >>= 1) lsum += __shfl_xor(lsum, o);
  if ((tid & 63) == 0) red[tid >> 6] = lsum;
  __syncthreads();
  const float inv = 1.f / (red[0] + red[1] + red[2] + red[3]);

  unsigned short* prow = (unsigned short*)row;  // bf16 P overlay, in place
  for (int i = tid * 8; i < nw; i += 2048) {
    bf16x8 o8;
#pragma unroll
    for (int j = 0; j < 8; ++j) o8[j] = (short)f2bf(buf[i + j] * inv);
    *(bf16x8*)(prow + i) = o8;
  }
}

// ---------------------------------------------------------------------------
extern "C" void kernel_launch(void* const* d_in, const int* in_sizes, int n_in,
                              void* d_out, int out_size, void* d_ws,
                              size_t ws_size, hipStream_t stream) {
  const float* x  = (const float*)d_in[0];
  const float* Wq = (const float*)d_in[1];
  const float* Wk = (const float*)d_in[2];
  const float* Wv = (const float*)d_in[3];
  const float* Wo = (const float*)d_in[4];
  const float* bo = (const float*)d_in[5];
  float* out = (float*)d_out;
  char* ws = (char*)d_ws;

  const size_t MB = 1024 * 1024;
  unsigned short* Wqb = (unsigned short*)(ws + 0 * MB);   // |
  unsigned short* Wkb = (unsigned short*)(ws + 2 * MB);   // | contiguous 6 MB
  unsigned short* Wvb = (unsigned short*)(ws + 4 * MB);   // | [3072][1024]
  unsigned short* Wob = (unsigned short*)(ws + 6 * MB);
  unsigned short* xb  = (unsigned short*)(ws + 8 * MB);   // 16 MB
  unsigned short* qb  = (unsigned short*)(ws + 24 * MB);  // 16 MB
  unsigned short* kb  = (unsigned short*)(ws + 40 * MB);  // 16 MB
  unsigned short* vTb = (unsigned short*)(ws + 56 * MB);  // 16 MB
  float* S            = (float*)(ws + 72 * MB);           // 128 MB (P overlays)
  unsigned short* attO = (unsigned short*)(ws + 8 * MB);  // alias xb (dead)
  (void)ws_size; (void)in_sizes; (void)n_in; (void)out_size;

  const dim3 blk(256);
  const long long TC = (long long)T * C;
  const long long TT = (long long)T * T;

  // 0) casts
  cast_all_bf16<<<12288, blk, 0, stream>>>(x, Wq, Wk, Wv, Wo,
                                           xb, Wqb, Wkb, Wvb, Wob);
  // 1) fused QKV projection: M=8192, N=3072, K=1024
  gemm_bt<3, false, 0><<<dim3(24, 64, 1), blk, 0, stream>>>(
      xb, Wqb, qb, kb, vTb, nullptr, 3072, C, C, C, 0, 0, 0, 1.f);
  // 2) S = q k^T * 1/sqrt(C)  (lower-triangle blocks only)
  gemm_bt<0, false, 1><<<dim3(32, 32, 2), blk, 0, stream>>>(
      qb, kb, S, nullptr, nullptr, nullptr, T, C, C, C, TC, TC, TT, 0.03125f);
  // 3) causal softmax, bf16 P written in place over S
  softmax_causal<<<Bz * T, blk, 0, stream>>>(S);
  // 4) attO = P @ v  (bf16 A, lda = 2T ushorts; K truncated; heavy-first)
  gemm_bt<1, false, 2><<<dim3(8, 32, 2), blk, 0, stream>>>(
      (const unsigned short*)S, vTb, attO, nullptr, nullptr, nullptr,
      C, T, 2 * T, T, 2 * TT, TC, TC, 1.f);
  // 5) out = attO @ Wo^T + bo
  gemm_bt<0, true, 0><<<dim3(8, 64, 1), blk, 0, stream>>>(
      attO, Wob, out, nullptr, nullptr, bo, C, C, C, C, 0, 0, 0, 1.f);
}

// Round 13
// 381.464 us; speedup vs baseline: 1.2637x; 1.1448x over previous
//
#include <hip/hip_runtime.h>

// ---------------------------------------------------------------------------
// Self-attention (single head, causal), B=2, T=4096, C=1024, fp32 in/out.
//   cast:   x, Wq|Wk|Wv (contiguous), Wo -> bf16
//   QKV:    one GEMM M=8192,N=3072,K=1024; epilogue routes q/k row-major,
//           v transposed (vT[b][d][t])
//   S:      q k^T * 1/32, fp32, lower-triangle blocks only
//   softmax: causal, in place; OUTPUT bf16 (P) overlaid on S rows (stride 2T)
//   PV:     attO = P @ v, K truncated at diagonal, heavy-first
//   O:      out = attO @ Wo^T + bo (fp32)
// GEMM: BK=64 (128B/row staging, full cachelines, half the barriers of BK=32)
// with st-style XOR swizzle (byte ^= (row&7)<<4), applied rule-#21-correctly:
// linear global_load_lds dest + inverse-swizzled GLOBAL source + swizzled
// LDS read. Fragment ds_read_b128 spreads 4 -> 8 distinct 16B col-slots.
// ---------------------------------------------------------------------------

typedef __attribute__((ext_vector_type(8))) short bf16x8;
typedef __attribute__((ext_vector_type(4))) float f32x4;

#define AS1 __attribute__((address_space(1)))
#define AS3 __attribute__((address_space(3)))

static constexpr int Bz = 2;
static constexpr int T = 4096;
static constexpr int C = 1024;

__device__ __forceinline__ unsigned short f2bf(float f) {
  unsigned int u = __float_as_uint(f);
  u += 0x7FFFu + ((u >> 16) & 1u);
  return (unsigned short)(u >> 16);
}

// ---------------------------------------------------------------------------
// Cast x + Wq/Wk/Wv/Wo fp32 -> bf16 (dsts laid out so Wq|Wk|Wv contiguous).
// ---------------------------------------------------------------------------
__global__ __launch_bounds__(256) void cast_all_bf16(
    const float* __restrict__ x, const float* __restrict__ wq,
    const float* __restrict__ wk, const float* __restrict__ wv,
    const float* __restrict__ wo, unsigned short* __restrict__ xb,
    unsigned short* __restrict__ wqb, unsigned short* __restrict__ wkb,
    unsigned short* __restrict__ wvb, unsigned short* __restrict__ wob) {
  const size_t NX = (size_t)Bz * T * C;       // 8388608
  const size_t NW = (size_t)C * C;            // 1048576
  size_t i4 = ((size_t)blockIdx.x * 256 + threadIdx.x) * 4;
  const float* src;
  unsigned short* dst;
  size_t off;
  if (i4 < NX) {
    src = x; dst = xb; off = i4;
  } else {
    size_t j = i4 - NX;
    int w = (int)(j >> 20);
    off = j & (NW - 1);
    if (w == 0)      { src = wq; dst = wqb; }
    else if (w == 1) { src = wk; dst = wkb; }
    else if (w == 2) { src = wv; dst = wvb; }
    else             { src = wo; dst = wob; }
  }
  float4 f = *(const float4*)(src + off);
  ushort4 u;
  u.x = f2bf(f.x); u.y = f2bf(f.y); u.z = f2bf(f.z); u.w = f2bf(f.w);
  *(ushort4*)(dst + off) = u;
}

// ---------------------------------------------------------------------------
// gemm_bt: C[m][n] = scale * sum_k A[m][k] * B[n][k]; A,B bf16 row-major.
//   OUT_MODE 0: fp32 out (optional bias), row stride N
//   OUT_MODE 1: bf16 out, row stride N
//   OUT_MODE 3: QKV split: gn<1024 -> Cp (q), <2048 -> Cp2 (k), else Cp3 = vT
//               transposed [b][d][t] with b = gm>>12, t = gm&4095
//   CAUSAL 0: none; 1: skip blocks bx>by (S); 2: ktiles=(by+1)*2, by reversed
//             heavy-first (PV)
// Tile 128x128, BK=64, 256 threads = 4 waves (2x2), mfma_f32_16x16x32_bf16,
// global_load_lds width-16 staging, XOR-swizzled LDS layout (see header).
// ---------------------------------------------------------------------------
template <int OUT_MODE, bool BIAS, int CAUSAL>
__global__ __launch_bounds__(256) void gemm_bt(
    const unsigned short* __restrict__ Ap, const unsigned short* __restrict__ Bp,
    void* __restrict__ Cp, void* __restrict__ Cp2, void* __restrict__ Cp3,
    const float* __restrict__ bias, int N, int K, int lda, int ldb,
    long long batchA, long long batchB, long long batchC, float scale) {
  const int bx = blockIdx.x, bz = blockIdx.z;
  const int by = (CAUSAL == 2) ? ((int)gridDim.y - 1 - (int)blockIdx.y)
                               : (int)blockIdx.y;
  if (CAUSAL == 1 && bx > by) return;
  const int m0 = by * 128, n0 = bx * 128;
  int ktiles = K / 64;
  if (CAUSAL == 2) ktiles = (by + 1) * 2;

  const unsigned short* Ab = Ap + (size_t)bz * batchA;
  const unsigned short* Bb = Bp + (size_t)bz * batchB;

  // [128 rows][64 bf16 = 128 B] per operand, swizzled storage (16 KB each)
  __shared__ __align__(16) unsigned short As[128 * 64];
  __shared__ __align__(16) unsigned short Bs[128 * 64];

  const int tid = threadIdx.x;
  const int lane = tid & 63;
  const int wid = tid >> 6;
  const int wr = wid >> 1, wc = wid & 1;
  const int lhi = lane >> 4, llo = lane & 15;

  f32x4 acc[4][4] = {};

  // Per-thread staging geometry (4 chunks of 1 KB per wave per operand).
  // Linear LDS dest byte for this lane in chunk i: wid*4096 + i*1024 + lane*16.
  // Source fetches the tile byte that the swizzled READ expects there:
  //   col_byte = (loff & 127) ^ ((row & 7) << 4)   (involution, 16B-aligned)
  for (int kt = 0; kt < ktiles; ++kt) {
    __syncthreads();
#pragma unroll
    for (int i = 0; i < 4; ++i) {
      const int loff = wid * 4096 + i * 1024 + lane * 16;
      const int row = loff >> 7;
      const int colb = (loff & 127) ^ ((row & 7) << 4);
      const char* srcA =
          (const char*)(Ab + (size_t)(m0 + row) * lda + kt * 64) + colb;
      __builtin_amdgcn_global_load_lds(
          (const AS1 char*)srcA,
          (AS3 char*)((char*)As + wid * 4096 + i * 1024), 16, 0, 0);
      const char* srcB =
          (const char*)(Bb + (size_t)(n0 + row) * ldb + kt * 64) + colb;
      __builtin_amdgcn_global_load_lds(
          (const AS1 char*)srcB,
          (AS3 char*)((char*)Bs + wid * 4096 + i * 1024), 16, 0, 0);
    }
    __syncthreads();
    // ---- compute: 32 MFMA (2 k-subtiles of 32) ----
    bf16x8 af[2][4], bfr[2][4];
    const int l7 = (llo & 7) << 4;  // row&7 == llo&7 for all fragment rows
#pragma unroll
    for (int ks = 0; ks < 2; ++ks) {
#pragma unroll
      for (int mi = 0; mi < 4; ++mi) {
        const int rowA = wr * 64 + mi * 16 + llo;
        af[ks][mi] = *(const bf16x8*)((const char*)As + rowA * 128 +
                                      ((ks * 64 + lhi * 16) ^ l7));
        const int rowB = wc * 64 + mi * 16 + llo;
        bfr[ks][mi] = *(const bf16x8*)((const char*)Bs + rowB * 128 +
                                       ((ks * 64 + lhi * 16) ^ l7));
      }
    }
#pragma unroll
    for (int ks = 0; ks < 2; ++ks)
#pragma unroll
      for (int mi = 0; mi < 4; ++mi)
#pragma unroll
        for (int ni = 0; ni < 4; ++ni)
          acc[mi][ni] = __builtin_amdgcn_mfma_f32_16x16x32_bf16(
              af[ks][mi], bfr[ks][ni], acc[mi][ni], 0, 0, 0);
  }

  // ---- epilogue ----
#pragma unroll
  for (int mi = 0; mi < 4; ++mi) {
#pragma unroll
    for (int ni = 0; ni < 4; ++ni) {
      f32x4 v = acc[mi][ni];
      const int r0 = wr * 64 + mi * 16 + lhi * 4;
      const int c = wc * 64 + ni * 16 + llo;
      const int gn = n0 + c;
#pragma unroll
      for (int j = 0; j < 4; ++j) {
        const int r = r0 + j;
        const int gm = m0 + r;
        float val = v[j] * scale;
        if (BIAS) val += bias[gn];
        if (OUT_MODE == 0) {
          float* Co = (float*)Cp + (size_t)bz * batchC;
          Co[(size_t)gm * N + gn] = val;
        } else if (OUT_MODE == 1) {
          unsigned short* Co = (unsigned short*)Cp + (size_t)bz * batchC;
          Co[(size_t)gm * N + gn] = f2bf(val);
        } else {  // OUT_MODE 3: QKV split
          if (gn < 1024) {
            ((unsigned short*)Cp)[(size_t)gm * 1024 + gn] = f2bf(val);
          } else if (gn < 2048) {
            ((unsigned short*)Cp2)[(size_t)gm * 1024 + (gn - 1024)] = f2bf(val);
          } else {
            const int b = gm >> 12, t = gm & (T - 1);
            ((unsigned short*)Cp3)[(size_t)b * T * C +
                                   (size_t)(gn - 2048) * T + t] = f2bf(val);
          }
        }
      }
    }
  }
}

// ---------------------------------------------------------------------------
// Causal row softmax. Reads fp32 S row [0, nw); writes bf16 P IN PLACE over
// the row start (stride stays T floats = 2T bf16). Row t: p for s<=t,
// zeros up to nw = next 128 boundary (exact extent the PV gemm reads).
// Safe in place: full row is in LDS before any global write.
// ---------------------------------------------------------------------------
__global__ __launch_bounds__(256) void softmax_causal(float* __restrict__ S) {
  const int r = blockIdx.x;           // 0 .. Bz*T-1
  const int b = r >> 12;              // T = 4096
  const int t = r & (T - 1);
  float* row = S + (size_t)b * T * T + (size_t)t * T;
  const int n = t + 1;
  const int nw = ((t >> 7) + 1) << 7;  // extent, multiple of 128

  __shared__ float buf[T];
  __shared__ float red[4];
  const int tid = threadIdx.x;

  float lmax = -1e30f;
  for (int i = tid * 4; i < nw; i += 1024) {
    float4 f = *(const float4*)(row + i);
    ((float4*)buf)[i >> 2] = f;
    if (i + 0 < n) lmax = fmaxf(lmax, f.x);
    if (i + 1 < n) lmax = fmaxf(lmax, f.y);
    if (i + 2 < n) lmax = fmaxf(lmax, f.z);
    if (i + 3 < n) lmax = fmaxf(lmax, f.w);
  }
#pragma unroll
  for (int o = 32; o > 0; o >>= 1) lmax = fmaxf(lmax, __shfl_xor(lmax, o));
  if ((tid & 63) == 0) red[tid >> 6] = lmax;
  __syncthreads();
  const float m = fmaxf(fmaxf(red[0], red[1]), fmaxf(red[2], red[3]));
  __syncthreads();

  float lsum = 0.f;
  for (int i = tid; i < nw; i += 256) {
    float p = (i < n) ? __expf(buf[i] - m) : 0.f;
    buf[i] = p;
    lsum += p;
  }
#pragma unroll
  for (int o = 32; o > 0; o >>= 1) lsum += __shfl_xor(lsum, o);
  if ((tid & 63) == 0) red[tid >> 6] = lsum;
  __syncthreads();
  const float inv = 1.f / (red[0] + red[1] + red[2] + red[3]);

  unsigned short* prow = (unsigned short*)row;  // bf16 P overlay, in place
  for (int i = tid * 8; i < nw; i += 2048) {
    bf16x8 o8;
#pragma unroll
    for (int j = 0; j < 8; ++j) o8[j] = (short)f2bf(buf[i + j] * inv);
    *(bf16x8*)(prow + i) = o8;
  }
}

// ---------------------------------------------------------------------------
extern "C" void kernel_launch(void* const* d_in, const int* in_sizes, int n_in,
                              void* d_out, int out_size, void* d_ws,
                              size_t ws_size, hipStream_t stream) {
  const float* x  = (const float*)d_in[0];
  const float* Wq = (const float*)d_in[1];
  const float* Wk = (const float*)d_in[2];
  const float* Wv = (const float*)d_in[3];
  const float* Wo = (const float*)d_in[4];
  const float* bo = (const float*)d_in[5];
  float* out = (float*)d_out;
  char* ws = (char*)d_ws;

  const size_t MB = 1024 * 1024;
  unsigned short* Wqb = (unsigned short*)(ws + 0 * MB);   // |
  unsigned short* Wkb = (unsigned short*)(ws + 2 * MB);   // | contiguous 6 MB
  unsigned short* Wvb = (unsigned short*)(ws + 4 * MB);   // | [3072][1024]
  unsigned short* Wob = (unsigned short*)(ws + 6 * MB);
  unsigned short* xb  = (unsigned short*)(ws + 8 * MB);   // 16 MB
  unsigned short* qb  = (unsigned short*)(ws + 24 * MB);  // 16 MB
  unsigned short* kb  = (unsigned short*)(ws + 40 * MB);  // 16 MB
  unsigned short* vTb = (unsigned short*)(ws + 56 * MB);  // 16 MB
  float* S            = (float*)(ws + 72 * MB);           // 128 MB (P overlays)
  unsigned short* attO = (unsigned short*)(ws + 8 * MB);  // alias xb (dead)
  (void)ws_size; (void)in_sizes; (void)n_in; (void)out_size;

  const dim3 blk(256);
  const long long TC = (long long)T * C;
  const long long TT = (long long)T * T;

  // 0) casts
  cast_all_bf16<<<12288, blk, 0, stream>>>(x, Wq, Wk, Wv, Wo,
                                           xb, Wqb, Wkb, Wvb, Wob);
  // 1) fused QKV projection: M=8192, N=3072, K=1024
  gemm_bt<3, false, 0><<<dim3(24, 64, 1), blk, 0, stream>>>(
      xb, Wqb, qb, kb, vTb, nullptr, 3072, C, C, C, 0, 0, 0, 1.f);
  // 2) S = q k^T * 1/sqrt(C)  (lower-triangle blocks only)
  gemm_bt<0, false, 1><<<dim3(32, 32, 2), blk, 0, stream>>>(
      qb, kb, S, nullptr, nullptr, nullptr, T, C, C, C, TC, TC, TT, 0.03125f);
  // 3) causal softmax, bf16 P written in place over S
  softmax_causal<<<Bz * T, blk, 0, stream>>>(S);
  // 4) attO = P @ v  (bf16 A, lda = 2T ushorts; K truncated; heavy-first)
  gemm_bt<1, false, 2><<<dim3(8, 32, 2), blk, 0, stream>>>(
      (const unsigned short*)S, vTb, attO, nullptr, nullptr, nullptr,
      C, T, 2 * T, T, 2 * TT, TC, TC, 1.f);
  // 5) out = attO @ Wo^T + bo
  gemm_bt<0, true, 0><<<dim3(8, 64, 1), blk, 0, stream>>>(
      attO, Wob, out, nullptr, nullptr, bo, C, C, C, C, 0, 0, 0, 1.f);
}